// Round 4
// baseline (326.062 us; speedup 1.0000x reference)
//
#include <hip/hip_runtime.h>
#include <cstdint>
#include <cstddef>

#define S_LEN 384
#define BATCH 256
#define DIM   192     // HH*WW
#define HID   100
#define G4    400     // 4*HID
#define NCLS  250

#define LOG2E  1.4426950408889634f
#define LOG2E2 2.8853900817779268f

typedef float    f32x4   __attribute__((ext_vector_type(4)));
typedef short    bf16x8  __attribute__((ext_vector_type(8)));
typedef _Float16 half2_t __attribute__((ext_vector_type(2)));
typedef _Float16 f16x4   __attribute__((ext_vector_type(4)));
typedef _Float16 f16x8   __attribute__((ext_vector_type(8)));

static __device__ __forceinline__ unsigned short f2bf(float f) {
    unsigned u = __float_as_uint(f);
    return (unsigned short)((u + 0x7FFFu + ((u >> 16) & 1u)) >> 16);   // RN
}

// DPP quad_perm cross-lane (VALU ~2cyc)
template<int CTRL>
static __device__ __forceinline__ float fdpp(float x) {
    return __int_as_float(
        __builtin_amdgcn_mov_dpp(__float_as_int(x), CTRL, 0xF, 0xF, true));
}
#define DPP_X1 0xB1   // quad_perm [1,0,3,2]  == xor 1
#define DPP_X2 0x4E   // quad_perm [2,3,0,1]  == xor 2
#define DPP_B0 0x00   // quad_perm [0,0,0,0]  broadcast lane0 of quad
#define DPP_B1 0x55   // quad_perm [1,1,1,1]
#define DPP_B2 0xAA   // quad_perm [2,2,2,2]
#define DPP_B3 0xFF   // quad_perm [3,3,3,3]

// Pin 13 half2 values into live VGPRs at this program point (insurance
// against load sinking; the real fix is amdgpu_waves_per_eu(2,2) below).
#define KEEP13(A)                                                             \
    asm volatile("" : "+v"(A[0]), "+v"(A[1]), "+v"(A[2]), "+v"(A[3]),         \
                      "+v"(A[4]), "+v"(A[5]), "+v"(A[6]), "+v"(A[7]),         \
                      "+v"(A[8]), "+v"(A[9]), "+v"(A[10]), "+v"(A[11]),       \
                      "+v"(A[12]));

// ---------------------------------------------------------------------------
// Prep: blocks [0,300): Wt_bf[k=400][d=192] = bf16(W[d][k]);
//       blocks [300,382): Ut4 — per-thread-(n,q) U fragments for the
//       512-thr scan (4 lanes per unit, quarter-h each):
//       Ut4[((n*4+q)*4+m)*13 + r] = half2 of U[j0][col], U[j0+1][col]
//       with j0 = 26q + 2r and col = (q^m)*HID + n  (XOR gate order so a
//       2-stage DPP butterfly lands gate q's full sum on lane q).
//       j >= 100 padded with zeros.
// ---------------------------------------------------------------------------
__global__ void prep(const float* __restrict__ W, const float* __restrict__ U,
                     unsigned short* __restrict__ Wt, half2_t* __restrict__ Ut4)
{
    int bid = blockIdx.x;
    if (bid < 300) {
        int i = bid * 256 + threadIdx.x;             // 76800 elements
        if (i >= G4 * DIM) return;
        int k = i / DIM, d = i - k * DIM;
        Wt[i] = f2bf(W[(size_t)d * G4 + k]);
    } else {
        int i = (bid - 300) * 256 + threadIdx.x;     // 100*4*4*13 = 20800
        if (i >= 20800) return;
        int n    = i / 208;
        int rem  = i - n * 208;
        int q    = rem / 52;
        int rem2 = rem - q * 52;
        int m    = rem2 / 13;
        int r    = rem2 - m * 13;
        int col  = (q ^ m) * HID + n;
        int j0   = 26 * q + 2 * r;
        half2_t v;
        v.x = (_Float16)(j0     < HID ? U[(size_t)j0       * G4 + col] : 0.0f);
        v.y = (_Float16)(j0 + 1 < HID ? U[(size_t)(j0 + 1) * G4 + col] : 0.0f);
        Ut4[i] = v;
    }
}

// ---------------------------------------------------------------------------
// Kernel 1: bf16 MFMA GEMM (byte-identical to the verified kernel).
//   pre[b][k][s] = x[b][s][:].W[:][k] + bias[k], stored f16.
// ---------------------------------------------------------------------------
__global__ __launch_bounds__(256, 2)
void gemm_pre(const float* __restrict__ x, const unsigned short* __restrict__ Wt,
              const float* __restrict__ bias, _Float16* __restrict__ preh,
              int s_start, int chunk)
{
    __shared__ unsigned int xs[64 * 100];    // rows: 200 bf16 (192 + 8 pad)
    __shared__ unsigned int wsh[400 * 20];   // rows: 40 bf16 (32 + 8 pad)

    const int t    = threadIdx.x;
    const int lane = t & 63;
    const int w    = t >> 6;
    const int nsb  = chunk >> 6;
    const int b    = blockIdx.x / nsb;
    const int sblk = blockIdx.x - b * nsb;
    const float* __restrict__ xb = x + ((size_t)b * S_LEN + s_start + sblk * 64) * DIM;

#pragma unroll
    for (int r = 0; r < 12; ++r) {
        int i = t + r * 256;                 // 3072 float4 = 64 rows x 48
        int row = i / 48, c4 = i - row * 48;
        float4 v = ((const float4*)(xb + (size_t)row * DIM))[c4];
        xs[row * 100 + c4 * 2]     = (unsigned)f2bf(v.x) | ((unsigned)f2bf(v.y) << 16);
        xs[row * 100 + c4 * 2 + 1] = (unsigned)f2bf(v.z) | ((unsigned)f2bf(v.w) << 16);
    }

    const int m = lane & 15, q = lane >> 4;

    float bv[25];
#pragma unroll
    for (int ct = 0; ct < 25; ++ct) bv[ct] = bias[ct * 16 + m];

    f32x4 acc[25];
#pragma unroll
    for (int ct = 0; ct < 25; ++ct) acc[ct] = (f32x4){0.f, 0.f, 0.f, 0.f};

    for (int dc = 0; dc < 6; ++dc) {
        if (dc) __syncthreads();             // protect previous chunk's readers
#pragma unroll
        for (int r = 0; r < 7; ++r) {
            int i = t + r * 256;
            if (i < 1600) {                  // 400 rows x 4 uint4 (32 bf16 = 64B)
                int k = i >> 2, u4 = i & 3;
                uint4 v = *(const uint4*)(Wt + (size_t)k * DIM + dc * 32 + u4 * 8);
                *(uint4*)(wsh + k * 20 + u4 * 4) = v;
            }
        }
        __syncthreads();

        const unsigned short* xp = (const unsigned short*)xs
                                   + (16 * w + m) * 200 + dc * 32 + q * 8;
        bf16x8 af = *(const bf16x8*)xp;
#pragma unroll
        for (int ct = 0; ct < 25; ++ct) {
            const unsigned short* bp = (const unsigned short*)wsh
                                       + (ct * 16 + m) * 40 + q * 8;
            bf16x8 bf = *(const bf16x8*)bp;
            acc[ct] = __builtin_amdgcn_mfma_f32_16x16x32_bf16(af, bf, acc[ct], 0, 0, 0);
        }
    }

    _Float16* __restrict__ pb = preh + (size_t)b * G4 * chunk + (size_t)sblk * 64
                                + 16 * w + q * 4;
#pragma unroll
    for (int ct = 0; ct < 25; ++ct) {
        f16x4 v;
        v[0] = (_Float16)(acc[ct][0] + bv[ct]);
        v[1] = (_Float16)(acc[ct][1] + bv[ct]);
        v[2] = (_Float16)(acc[ct][2] + bv[ct]);
        v[3] = (_Float16)(acc[ct][3] + bv[ct]);
        *(f16x4*)(pb + (size_t)(ct * 16 + m) * chunk) = v;
    }
}

// ---------------------------------------------------------------------------
// Kernel 2 (round 4): byte-identical structure to the verified round-1 scan
//   (512 thr, 4 lanes/unit, XOR-butterfly gates), with the occupancy target
//   PINNED at 2 waves/EU: grid = 256 blocks = 1 block/CU = 8 waves/CU, so
//   any register budget targeting more occupancy is pure waste. With
//   min=max=2, the VGPR budget is 128/wave and the 52 loop-invariant U
//   fragments stay resident instead of being rematerialized every step
//   (the ~400 cy/step re-fetch that r0-r3 all paid).
// ---------------------------------------------------------------------------
__global__ __launch_bounds__(512)
__attribute__((amdgpu_waves_per_eu(2, 2)))
void lstm_scan(const _Float16* __restrict__ preh, const half2_t* __restrict__ Ut4,
               const float* __restrict__ Wd, const float* __restrict__ bd,
               float* __restrict__ out, float* __restrict__ state,
               int nsteps, int first, int last)
{
    // h quarters: [buf][q][40] f16; 80B stride => the 4 b128 read addresses
    // land on disjoint bank groups (0-3 / 20-23 / 8-11 / 28-31).
    __shared__ __align__(16) _Float16 h2[2][4][40];
    __shared__ __align__(16) float hf32[HID];

    const int b  = blockIdx.x;
    const int t  = threadIdx.x;
    const int q  = t & 3;
    const int nr = t >> 2;                   // 0..127
    const bool active = (nr < HID);
    const int n  = active ? nr : HID - 1;    // keep dummy quads for SIMD balance
    const int wq = n / 26, wi = n - wq * 26;

    // Uc[m][r]: gate (q^m), h-elems 26q+2r, 26q+2r+1
    half2_t Uc[4][13];
#pragma unroll
    for (int m = 0; m < 4; ++m) {
        const half2_t* up = Ut4 + (size_t)((n * 4 + q) * 4 + m) * 13;
#pragma unroll
        for (int r = 0; r < 13; ++r) Uc[m][r] = up[r];
    }

    if (t < 320) ((_Float16*)h2)[t] = (_Float16)0.f;   // zero both bufs + padding
    float c;
    if (first) {
        c = 0.f;
        __syncthreads();
    } else {
        c = state[BATCH * HID + b * HID + n];          // redundant across quad
        __syncthreads();                               // zeros visible
        if (t < HID) h2[0][t / 26][t - (t / 26) * 26] = (_Float16)state[b * HID + t];
        __syncthreads();
    }

    // one z stream per lane: gate q of unit n, contiguous in s
    const _Float16* __restrict__ zp = preh + ((size_t)b * G4 + q * HID + n) * nsteps;

    // lane activation: q==2 -> tanh (gate g), else sigmoid (i/f/o)
    const float scale = (q == 2) ? -LOG2E2 : -LOG2E;
    const float Aact  = (q == 2) ? 2.0f : 1.0f;
    const float Bact  = (q == 2) ? -1.0f : 0.0f;

    float hn_last = 0.f;

    auto step = [&](float zk, int cur) {
        const _Float16* hb = &h2[cur][q][0];
        f16x8   g0 = *(const f16x8*)(hb);
        f16x8   g1 = *(const f16x8*)(hb + 8);
        f16x8   g2 = *(const f16x8*)(hb + 16);
        half2_t g3 = *(const half2_t*)(hb + 24);
        half2_t hp[13];
        hp[0]  = __builtin_shufflevector(g0, g0, 0, 1);
        hp[1]  = __builtin_shufflevector(g0, g0, 2, 3);
        hp[2]  = __builtin_shufflevector(g0, g0, 4, 5);
        hp[3]  = __builtin_shufflevector(g0, g0, 6, 7);
        hp[4]  = __builtin_shufflevector(g1, g1, 0, 1);
        hp[5]  = __builtin_shufflevector(g1, g1, 2, 3);
        hp[6]  = __builtin_shufflevector(g1, g1, 4, 5);
        hp[7]  = __builtin_shufflevector(g1, g1, 6, 7);
        hp[8]  = __builtin_shufflevector(g2, g2, 0, 1);
        hp[9]  = __builtin_shufflevector(g2, g2, 2, 3);
        hp[10] = __builtin_shufflevector(g2, g2, 4, 5);
        hp[11] = __builtin_shufflevector(g2, g2, 6, 7);
        hp[12] = g3;

        // P[m] = partial of gate (q^m) over quarter q; 4 parallel chains of 13
        float p0 = 0.f, p1 = 0.f, p2 = 0.f, p3 = 0.f;
#pragma unroll
        for (int r = 0; r < 13; ++r) {
            p0 = __builtin_amdgcn_fdot2(Uc[0][r], hp[r], p0, false);
            p1 = __builtin_amdgcn_fdot2(Uc[1][r], hp[r], p1, false);
            p2 = __builtin_amdgcn_fdot2(Uc[2][r], hp[r], p2, false);
            p3 = __builtin_amdgcn_fdot2(Uc[3][r], hp[r], p3, false);
        }
        // butterfly: after xor1, lane q holds gate q (and q^2) over {q,q^1};
        // after xor2, lane q holds gate q over all four quarters.
        float s0 = p0 + fdpp<DPP_X1>(p1);
        float s2 = p2 + fdpp<DPP_X1>(p3);
        float a  = s0 + fdpp<DPP_X2>(s2) + zk;

        float v = fmaf(Aact,
                       __builtin_amdgcn_rcpf(1.0f + __builtin_amdgcn_exp2f(scale * a)),
                       Bact);                           // i/f/o sigmoid, g tanh

        float bi = fdpp<DPP_B0>(v);                     // gate i (lane 0)
        float bf = fdpp<DPP_B1>(v);                     // gate f (lane 1)
        float bg = fdpp<DPP_B2>(v);                     // gate g (lane 2)
        float bo = fdpp<DPP_B3>(v);                     // gate o (lane 3)

        c = fmaf(bf, c, bi * bg);                       // redundant on all 4 lanes
        float tc = fmaf(2.0f,
                        __builtin_amdgcn_rcpf(1.0f + __builtin_amdgcn_exp2f(-LOG2E2 * c)),
                        -1.0f);
        float hn = bo * tc;
        if (q == 0 && active) h2[cur ^ 1][wq][wi] = (_Float16)hn;
        hn_last = hn;
        __syncthreads();
    };

    f16x8 zv = *(const f16x8*)(zp);
    for (int s8 = 0; s8 < nsteps; s8 += 8) {            // nsteps % 8 == 0
        // pin U fragments: must stay live in VGPRs across the whole scan
        KEEP13(Uc[0]) KEEP13(Uc[1]) KEEP13(Uc[2]) KEEP13(Uc[3])
        f16x8 zvn = zv;
        if (s8 + 8 < nsteps) zvn = *(const f16x8*)(zp + s8 + 8);   // prefetch
#pragma unroll
        for (int k = 0; k < 8; ++k)
            step((float)zv[k], k & 1);
        zv = zvn;
    }

    if (last) {
        if (q == 0 && active) hf32[n] = hn_last;
        __syncthreads();
        if (t < NCLS) {
            float acc2 = bd[t];
            const float4* h4 = (const float4*)hf32;
#pragma unroll 5
            for (int j4 = 0; j4 < 25; ++j4) {
                float4 hv = h4[j4];
                acc2 = fmaf(hv.x, Wd[(size_t)(4 * j4 + 0) * NCLS + t], acc2);
                acc2 = fmaf(hv.y, Wd[(size_t)(4 * j4 + 1) * NCLS + t], acc2);
                acc2 = fmaf(hv.z, Wd[(size_t)(4 * j4 + 2) * NCLS + t], acc2);
                acc2 = fmaf(hv.w, Wd[(size_t)(4 * j4 + 3) * NCLS + t], acc2);
            }
            out[(size_t)b * NCLS + t] = acc2;
        }
    } else {
        if (q == 0 && active) {
            state[b * HID + n] = hn_last;
            state[BATCH * HID + b * HID + n] = c;
        }
    }
}

// ---------------------------------------------------------------------------
extern "C" void kernel_launch(void* const* d_in, const int* in_sizes, int n_in,
                              void* d_out, int out_size, void* d_ws, size_t ws_size,
                              hipStream_t stream)
{
    const float* x    = (const float*)d_in[0];
    const float* W    = (const float*)d_in[1];
    const float* U    = (const float*)d_in[2];
    const float* bias = (const float*)d_in[3];
    const float* Wd   = (const float*)d_in[4];
    const float* bd   = (const float*)d_in[5];
    float* out = (float*)d_out;

    // ws (dwords): [state 51200][Ut4 20800][Wt_bf 38400][preh f16: chunk*51200 dw]
    const size_t fixed_dw = 51200 + 20800 + 38400;   // 110400
    int chunk = 64;
    if      (ws_size >= (fixed_dw + (size_t)384 * 51200) * 4) chunk = 384;
    else if (ws_size >= (fixed_dw + (size_t)192 * 51200) * 4) chunk = 192;
    const int nchunks = S_LEN / chunk;

    unsigned int* wsb = (unsigned int*)d_ws;
    float*          state = (float*)wsb;
    half2_t*        Ut4   = (half2_t*)(wsb + 51200);
    unsigned short* Wt    = (unsigned short*)(wsb + 72000);
    _Float16*       preh  = (_Float16*)(wsb + 110400);

    prep<<<382, 256, 0, stream>>>(W, U, Wt, Ut4);

    for (int ci = 0; ci < nchunks; ++ci) {
        const int s0 = ci * chunk;
        gemm_pre<<<BATCH * (chunk >> 6), 256, 0, stream>>>(x, Wt, bias, preh, s0, chunk);
        lstm_scan<<<BATCH, 512, 0, stream>>>(preh, Ut4, Wd, bd, out, state,
                                             chunk, ci == 0 ? 1 : 0,
                                             ci == nchunks - 1 ? 1 : 0);
    }
}

// Round 5
// 314.242 us; speedup vs baseline: 1.0376x; 1.0376x over previous
//
#include <hip/hip_runtime.h>
#include <cstdint>
#include <cstddef>

#define S_LEN 384
#define BATCH 256
#define DIM   192     // HH*WW
#define HID   100
#define G4    400     // 4*HID
#define NCLS  250

#define WSTEPS 16     // z-tile window (MFMA M-dim = 16 timesteps)
#define NWIN   24     // 384 / 16
#define NTILES 28     // 448 cols (4 gates x 112) / 16
#define NKC    6      // 192 / 32 k-chunks

#define LOG2E  1.4426950408889634f
#define LOG2E2 2.8853900817779268f

typedef float    f32x4   __attribute__((ext_vector_type(4)));
typedef short    bf16x8  __attribute__((ext_vector_type(8)));
typedef _Float16 half2_t __attribute__((ext_vector_type(2)));
typedef _Float16 f16x4   __attribute__((ext_vector_type(4)));
typedef _Float16 f16x8   __attribute__((ext_vector_type(8)));

static __device__ __forceinline__ unsigned short f2bf(float f) {
    unsigned u = __float_as_uint(f);
    return (unsigned short)((u + 0x7FFFu + ((u >> 16) & 1u)) >> 16);   // RNE
}

// packed f32x2 -> bf16x2 (RNE), gfx950 has no builtin (learn_hip m240)
static __device__ __forceinline__ unsigned cvtpk(float a, float b) {
    unsigned r;
    asm("v_cvt_pk_bf16_f32 %0, %1, %2" : "=v"(r) : "v"(a), "v"(b));
    return r;
}

// DPP quad_perm cross-lane (VALU ~2cyc)
template<int CTRL>
static __device__ __forceinline__ float fdpp(float x) {
    return __int_as_float(
        __builtin_amdgcn_mov_dpp(__float_as_int(x), CTRL, 0xF, 0xF, true));
}
#define DPP_X1 0xB1   // quad_perm [1,0,3,2]  == xor 1
#define DPP_X2 0x4E   // quad_perm [2,3,0,1]  == xor 2
#define DPP_B0 0x00   // quad_perm [0,0,0,0]  broadcast lane0 of quad
#define DPP_B1 0x55   // quad_perm [1,1,1,1]
#define DPP_B2 0xAA   // quad_perm [2,2,2,2]
#define DPP_B3 0xFF   // quad_perm [3,3,3,3]

// ---------------------------------------------------------------------------
// Prep:
//  blocks [0,336): Wf — W pre-transformed into MFMA B-fragments (bf16):
//    Wf[((ct*6+kc)*64+lane)*8+e] = bf16(W[d][gate*100+unit]), where
//    gate=ct/7, unit=(ct%7)*16+(lane&15) (0-pad unit>=100),
//    d = kc*32 + (lane>>4)*8 + e.  (identical mapping to the verified
//    gemm_pre B operand: col=lane&15, k=(lane>>4)*8+e)
//  blocks [336,418): Ut4 — unchanged U fragment layout for the scan.
// ---------------------------------------------------------------------------
__global__ void prep(const float* __restrict__ W, const float* __restrict__ U,
                     unsigned short* __restrict__ Wf, half2_t* __restrict__ Ut4)
{
    int bid = blockIdx.x;
    if (bid < 336) {
        int i = bid * 256 + threadIdx.x;          // 336*256 = 86016 exactly
        int e    = i & 7;
        int fi   = i >> 3;
        int lane = fi & 63;
        int ck   = fi >> 6;                       // (ct*6+kc) < 168
        int ct   = ck / 6, kc = ck - ct * 6;
        int m    = lane & 15, q = lane >> 4;
        int gate = ct / 7, jj = ct - gate * 7;
        int unit = jj * 16 + m;
        int d    = kc * 32 + q * 8 + e;           // < 192 always
        float v  = (unit < HID) ? W[(size_t)d * G4 + gate * HID + unit] : 0.0f;
        Wf[i] = f2bf(v);
    } else {
        int i = (bid - 336) * 256 + threadIdx.x;  // 100*4*4*13 = 20800
        if (i >= 20800) return;
        int n    = i / 208;
        int rem  = i - n * 208;
        int q    = rem / 52;
        int rem2 = rem - q * 52;
        int mm   = rem2 / 13;
        int r    = rem2 - mm * 13;
        int col  = (q ^ mm) * HID + n;
        int j0   = 26 * q + 2 * r;
        half2_t v;
        v.x = (_Float16)(j0     < HID ? U[(size_t)j0       * G4 + col] : 0.0f);
        v.y = (_Float16)(j0 + 1 < HID ? U[(size_t)(j0 + 1) * G4 + col] : 0.0f);
        Ut4[i] = v;
    }
}

// ---------------------------------------------------------------------------
// Fused kernel: one block per batch, 512 thr (8 waves, 2/SIMD), single
// launch for all 384 steps.
//   Scan core: VERIFIED r1 structure (4 lanes/unit, XOR-butterfly, one
//   barrier/step). z now comes from LDS zbuf instead of global preh.
//   Produce phase (once per 16-step window, double-buffered zbuf):
//   z-tile [16 steps x 448 gate-cols] = x_tile @ W + bias via 16x16x32
//   bf16 MFMA. Wave w owns 4 (w<4) or 3 (w>=4) col-tiles; A (x rows,
//   f32->bf16 via v_cvt_pk_bf16_f32) prefetched one window ahead into
//   registers; B fragments read per window from L2-hot Wf.
//   zbuf col-major [448][16]: producer lane writes f16x4 (D rows q4*4+e);
//   scan thread reads its 16-step window as 2x ds_read_b128.
//   This deletes gemm_pre (~130us: 78MB scattered preh writes + 39MB
//   re-read) entirely.
// ---------------------------------------------------------------------------
__global__ __launch_bounds__(512)
__attribute__((amdgpu_waves_per_eu(2, 2)))
void scan_fused(const float* __restrict__ x, const unsigned short* __restrict__ Wf,
                const half2_t* __restrict__ Ut4, const float* __restrict__ bias,
                const float* __restrict__ Wd, const float* __restrict__ bd,
                float* __restrict__ out)
{
    __shared__ __align__(16) _Float16 h2[2][4][40];
    __shared__ __align__(16) float hf32[HID];
    __shared__ __align__(16) _Float16 zbuf[2][448 * WSTEPS];   // 28.7 KB

    const int b  = blockIdx.x;
    const int t  = threadIdx.x;

    // ---- scan roles ----
    const int q  = t & 3;
    const int nr = t >> 2;                   // 0..127
    const bool active = (nr < HID);
    const int n  = active ? nr : HID - 1;
    const int wq = n / 26, wi = n - wq * 26;

    // ---- gemm roles ----
    const int lane = t & 63;
    const int w    = t >> 6;
    const int m    = lane & 15;
    const int q4   = lane >> 4;
    const int ntile = (w < 4) ? 4 : 3;
    const int tbase = (w < 4) ? (w * 4) : (16 + (w - 4) * 3);

    float bv[4];
#pragma unroll
    for (int i = 0; i < 4; ++i) {
        int ct   = tbase + i;
        int gate = ct / 7, jj = ct - gate * 7;
        int unit = jj * 16 + m;
        bv[i] = (i < ntile && unit < HID) ? bias[gate * HID + unit] : 0.0f;
    }

    const float* __restrict__ xb = x + (size_t)b * S_LEN * DIM;
    float4 xv[NKC][2];                       // next window's x rows (48 VGPR)

#define LOADX(S0)                                                             \
    { int xr = (S0) + m;                                                      \
      _Pragma("unroll")                                                       \
      for (int kc = 0; kc < NKC; ++kc) {                                      \
          const float* p = xb + (size_t)xr * DIM + kc * 32 + q4 * 8;          \
          xv[kc][0] = *(const float4*)p;                                      \
          xv[kc][1] = *(const float4*)(p + 4);                                \
      } }

#define PRODUCE(NB)                                                           \
    { bf16x8 Af[NKC];                                                         \
      _Pragma("unroll")                                                       \
      for (int kc = 0; kc < NKC; ++kc) {                                      \
          int4 ai;                                                            \
          ai.x = (int)cvtpk(xv[kc][0].x, xv[kc][0].y);                        \
          ai.y = (int)cvtpk(xv[kc][0].z, xv[kc][0].w);                        \
          ai.z = (int)cvtpk(xv[kc][1].x, xv[kc][1].y);                        \
          ai.w = (int)cvtpk(xv[kc][1].z, xv[kc][1].w);                        \
          Af[kc] = *(bf16x8*)&ai;                                             \
      }                                                                       \
      _Pragma("unroll")                                                       \
      for (int i = 0; i < 4; ++i) if (i < ntile) {                            \
          int ct = tbase + i;                                                 \
          const unsigned short* bp = Wf + ((size_t)ct * NKC * 64 + lane) * 8; \
          f32x4 acc = {bv[i], bv[i], bv[i], bv[i]};                           \
          _Pragma("unroll")                                                   \
          for (int kc = 0; kc < NKC; ++kc) {                                  \
              bf16x8 Bf = *(const bf16x8*)(bp + (size_t)kc * 512);            \
              acc = __builtin_amdgcn_mfma_f32_16x16x32_bf16(Af[kc], Bf, acc, 0, 0, 0); \
          }                                                                   \
          f16x4 zq;                                                           \
          zq[0] = (_Float16)acc[0]; zq[1] = (_Float16)acc[1];                 \
          zq[2] = (_Float16)acc[2]; zq[3] = (_Float16)acc[3];                 \
          *(f16x4*)&zbuf[NB][(ct * 16 + m) * WSTEPS + q4 * 4] = zq;           \
      } }

    // ---- scan U fragments (verified r1 layout) ----
    half2_t Uc[4][13];
#pragma unroll
    for (int mm = 0; mm < 4; ++mm) {
        const half2_t* up = Ut4 + (size_t)((n * 4 + q) * 4 + mm) * 13;
#pragma unroll
        for (int r = 0; r < 13; ++r) Uc[mm][r] = up[r];
    }

    if (t < 320) ((_Float16*)h2)[t] = (_Float16)0.f;
    float c = 0.f;

    // prologue: z(0) into zbuf[0]; prefetch x(1)
    LOADX(0);
    PRODUCE(0);
    LOADX(WSTEPS);
    __syncthreads();                         // h2 zeros + zbuf[0] visible

    const float scale = (q == 2) ? -LOG2E2 : -LOG2E;
    const float Aact  = (q == 2) ? 2.0f : 1.0f;
    const float Bact  = (q == 2) ? -1.0f : 0.0f;

    float hn_last = 0.f;

    auto step = [&](float zk, int cur) {
        const _Float16* hb = &h2[cur][q][0];
        f16x8   g0 = *(const f16x8*)(hb);
        f16x8   g1 = *(const f16x8*)(hb + 8);
        f16x8   g2 = *(const f16x8*)(hb + 16);
        half2_t g3 = *(const half2_t*)(hb + 24);
        half2_t hp[13];
        hp[0]  = __builtin_shufflevector(g0, g0, 0, 1);
        hp[1]  = __builtin_shufflevector(g0, g0, 2, 3);
        hp[2]  = __builtin_shufflevector(g0, g0, 4, 5);
        hp[3]  = __builtin_shufflevector(g0, g0, 6, 7);
        hp[4]  = __builtin_shufflevector(g1, g1, 0, 1);
        hp[5]  = __builtin_shufflevector(g1, g1, 2, 3);
        hp[6]  = __builtin_shufflevector(g1, g1, 4, 5);
        hp[7]  = __builtin_shufflevector(g1, g1, 6, 7);
        hp[8]  = __builtin_shufflevector(g2, g2, 0, 1);
        hp[9]  = __builtin_shufflevector(g2, g2, 2, 3);
        hp[10] = __builtin_shufflevector(g2, g2, 4, 5);
        hp[11] = __builtin_shufflevector(g2, g2, 6, 7);
        hp[12] = g3;

        float p0 = 0.f, p1 = 0.f, p2 = 0.f, p3 = 0.f;
#pragma unroll
        for (int r = 0; r < 13; ++r) {
            p0 = __builtin_amdgcn_fdot2(Uc[0][r], hp[r], p0, false);
            p1 = __builtin_amdgcn_fdot2(Uc[1][r], hp[r], p1, false);
            p2 = __builtin_amdgcn_fdot2(Uc[2][r], hp[r], p2, false);
            p3 = __builtin_amdgcn_fdot2(Uc[3][r], hp[r], p3, false);
        }
        float s0 = p0 + fdpp<DPP_X1>(p1);
        float s2 = p2 + fdpp<DPP_X1>(p3);
        float a  = s0 + fdpp<DPP_X2>(s2) + zk;

        float v = fmaf(Aact,
                       __builtin_amdgcn_rcpf(1.0f + __builtin_amdgcn_exp2f(scale * a)),
                       Bact);

        float bi = fdpp<DPP_B0>(v);
        float bf = fdpp<DPP_B1>(v);
        float bg = fdpp<DPP_B2>(v);
        float bo = fdpp<DPP_B3>(v);

        c = fmaf(bf, c, bi * bg);
        float tc = fmaf(2.0f,
                        __builtin_amdgcn_rcpf(1.0f + __builtin_amdgcn_exp2f(-LOG2E2 * c)),
                        -1.0f);
        float hn = bo * tc;
        if (q == 0 && active) h2[cur ^ 1][wq][wi] = (_Float16)hn;
        hn_last = hn;
        __syncthreads();
    };

    const int col = q * 112 + n;             // zbuf column for (gate q, unit n)

    for (int j = 0; j < NWIN; ++j) {
        // this window's 16 z values (written >=16 barriers ago)
        f16x8 zA = *(const f16x8*)&zbuf[j & 1][col * WSTEPS];
        f16x8 zB = *(const f16x8*)&zbuf[j & 1][col * WSTEPS + 8];
        // produce next window into the other buffer (its previous readers
        // finished at window j-1's last barrier)
        if (j < NWIN - 1) PRODUCE((j + 1) & 1);
        if (j < NWIN - 2) LOADX((j + 2) * WSTEPS);
#pragma unroll
        for (int k = 0; k < 8; ++k) step((float)zA[k], k & 1);
#pragma unroll
        for (int k = 0; k < 8; ++k) step((float)zB[k], k & 1);
    }

    // ---- classifier tail ----
    if (q == 0 && active) hf32[n] = hn_last;
    __syncthreads();
    if (t < NCLS) {
        float acc2 = bd[t];
        const float4* h4 = (const float4*)hf32;
#pragma unroll 5
        for (int j4 = 0; j4 < 25; ++j4) {
            float4 hv = h4[j4];
            acc2 = fmaf(hv.x, Wd[(size_t)(4 * j4 + 0) * NCLS + t], acc2);
            acc2 = fmaf(hv.y, Wd[(size_t)(4 * j4 + 1) * NCLS + t], acc2);
            acc2 = fmaf(hv.z, Wd[(size_t)(4 * j4 + 2) * NCLS + t], acc2);
            acc2 = fmaf(hv.w, Wd[(size_t)(4 * j4 + 3) * NCLS + t], acc2);
        }
        out[(size_t)b * NCLS + t] = acc2;
    }
}

// ---------------------------------------------------------------------------
extern "C" void kernel_launch(void* const* d_in, const int* in_sizes, int n_in,
                              void* d_out, int out_size, void* d_ws, size_t ws_size,
                              hipStream_t stream)
{
    const float* x    = (const float*)d_in[0];
    const float* W    = (const float*)d_in[1];
    const float* U    = (const float*)d_in[2];
    const float* bias = (const float*)d_in[3];
    const float* Wd   = (const float*)d_in[4];
    const float* bd   = (const float*)d_in[5];
    float* out = (float*)d_out;

    // ws (dwords): [Wf bf16: 86016 shorts = 43008 dw][Ut4: 20800 dw]
    unsigned int* wsb = (unsigned int*)d_ws;
    unsigned short* Wf  = (unsigned short*)wsb;
    half2_t*        Ut4 = (half2_t*)(wsb + 43008);

    prep<<<418, 256, 0, stream>>>(W, U, Wf, Ut4);
    scan_fused<<<BATCH, 512, 0, stream>>>(x, Wf, Ut4, bias, Wd, bd, out);
}